// Round 20
// baseline (127.275 us; speedup 1.0000x reference)
//
#include <hip/hip_runtime.h>
#include <hip/hip_bf16.h>
#include <math.h>

#define CIN 128
#define COUT 64
#define BSAMP 64      // samples in batch (fixed by problem)
#define NFINE 10242   // fine nodes per sample (fixed by problem)
#define NCOARSE 2562  // coarse nodes per sample (fixed by problem)
#define NRNG 4        // node-ranges per sample
#define RS 2561       // ceil(NFINE / NRNG)
#define HT 1024       // threads for build kernel
#define NCLS 17       // degree classes 0..15 and >=16
#define SEGCAP 20480  // slots per (sample,range) segment; mean 15360, sigma ~107
#define CPAD 16       // cursor padding (ints) -> one 64 B line per cursor
#define EPB 2048      // edges per prep block (8 per thread)

typedef float f32x4 __attribute__((ext_vector_type(4)));
typedef short s16x8 __attribute__((ext_vector_type(8)));

// Bucket-scatter prep with per-block LDS staging; 8 edges per thread.
__global__ __launch_bounds__(256) void k_prep(const int4* __restrict__ src4, const int4* __restrict__ dst4,
                                              unsigned* __restrict__ pk, int* __restrict__ cur,
                                              int EPS, int bps) {
    __shared__ unsigned bbuf[NRNG][EPB];
    __shared__ int bcnt[NRNG];
    __shared__ int gb[NRNG];
    int t = threadIdx.x;
    int b  = blockIdx.x / bps;
    int il0 = (blockIdx.x % bps) * 512 + t;
    int n4 = EPS / 4;
    if (t < NRNG) bcnt[t] = 0;
    __syncthreads();
    int base = b * NFINE;
#pragma unroll
    for (int half = 0; half < 2; ++half) {
        int il = il0 + half * 256;
        if (il < n4) {
            size_t i = (size_t)b * n4 + il;
            int4 s = src4[i], d = dst4[i];
#define COMP(c) { \
            int ls = d.c - base; \
            if ((unsigned)ls < (unsigned)NFINE) { \
                int rri = ls / RS; \
                int sl = s.c - base; \
                unsigned rc = ((unsigned)sl < (unsigned)NCOARSE) ? (unsigned)(b * NCOARSE + sl + 1) : 0u; \
                unsigned pv = ((unsigned)(ls - rri * RS) << 18) | rc; \
                int p = atomicAdd(&bcnt[rri], 1); \
                bbuf[rri][p] = pv; } }
            COMP(x) COMP(y) COMP(z) COMP(w)
#undef COMP
        }
    }
    __syncthreads();
    if (t < NRNG) gb[t] = atomicAdd(&cur[(b * NRNG + t) * CPAD], bcnt[t]);
    __syncthreads();
#pragma unroll
    for (int rr = 0; rr < NRNG; ++rr) {
        int n = bcnt[rr];
        int g0 = gb[rr];
        unsigned* seg = pk + (size_t)(b * NRNG + rr) * SEGCAP;
        for (int i = t; i < n; i += 256) {
            int pos = g0 + i;
            if (pos < SEGCAP) seg[pos] = bbuf[rr][i];
        }
    }
}

// CSR build (round-19 version: shfl wave-scan, 2 barriers).
__global__ __launch_bounds__(HT) void k_build(const unsigned* __restrict__ pk, const int* __restrict__ cur,
                                              int2* __restrict__ meta, float* __restrict__ normc,
                                              int* __restrict__ vals, int* __restrict__ ord,
                                              int* __restrict__ gctr) {
    __shared__ int   lh[RS];
    __shared__ int   wsum[16];
    __shared__ int   ccnt[NCLS];
    __shared__ int   gbase;
    int t = threadIdx.x;
    int lane = t & 63, wv = t >> 6;
    int b = blockIdx.x / NRNG, r = blockIdx.x % NRNG;
    int lo = r * RS;
    int nlocal = min(RS, NFINE - lo);
    int rebase = b * NFINE + lo;
    for (int j = t; j < nlocal; j += HT) lh[j] = 0;
    if (t < NCLS) ccnt[t] = 0;
    __syncthreads();

    const unsigned* seg = pk + (size_t)(b * NRNG + r) * SEGCAP;
    int ne = min(cur[(b * NRNG + r) * CPAD], SEGCAP);
    for (int i = t; i < ne; i += HT) {
        unsigned u = seg[i];
        int l = (int)(u >> 18);
        int rc = (int)(u & 0x3FFFFu);
        if (l < nlocal) atomicAdd(&lh[l], 1 + (rc ? 65536 : 0));
    }
    __syncthreads();

    int mj[3], degk[3], selfk[3], cls[3], rank[3];
    int psum = 0;
#pragma unroll
    for (int k = 0; k < 3; ++k) {
        int idx = t + k * HT;
        int m = 0, dg = 0, sf = 0;
        if (idx < nlocal) {
            int c = lh[idx];
            int slocal = lo + idx;
            sf = (slocal < NCOARSE) ? (b * NCOARSE + slocal + 1) : 0;
            m = (c >> 16) + (sf ? 1 : 0);
            dg = (c & 0xFFFF) + 1;
            cls[k] = min(m, NCLS - 1);
            rank[k] = atomicAdd(&ccnt[cls[k]], 1);
        }
        mj[k] = m; degk[k] = dg; selfk[k] = sf;
        psum += m;
    }
    int v = psum;
#pragma unroll
    for (int off = 1; off < 64; off <<= 1) {
        int u = __shfl_up(v, off);
        if (lane >= off) v += u;
    }
    if (lane == 63) wsum[wv] = v;
    __syncthreads();
    if (t == 0) {
        int run = 0;
#pragma unroll
        for (int w = 0; w < 16; ++w) { int x2 = wsum[w]; wsum[w] = run; run += x2; }
        int run2 = 0;
#pragma unroll
        for (int c = 0; c < NCLS; ++c) { int x2 = ccnt[c]; ccnt[c] = run2; run2 += x2; }
    }
    __syncthreads();
    int inc = v + wsum[wv];
    if (t == HT - 1) gbase = atomicAdd(gctr, inc);
    __syncthreads();

    int run = gbase + inc - psum;
#pragma unroll
    for (int k = 0; k < 3; ++k) {
        int idx = t + k * HT;
        if (idx < nlocal) {
            int gf = rebase + idx;
            meta[gf] = make_int2(run, mj[k] | (degk[k] << 16));
            ord[rebase + ccnt[cls[k]] + rank[k]] = gf;
            int cur2 = run;
            if (selfk[k]) {
                int rv = selfk[k] - 1;
                normc[rv] = rsqrtf((float)degk[k]);
                vals[cur2] = rv;
                ++cur2;
            }
            lh[idx] = cur2;
            run += mj[k];
        }
    }
    __syncthreads();

    for (int i = t; i < ne; i += HT) {
        unsigned u = seg[i];
        int l = (int)(u >> 18);
        int rc = (int)(u & 0x3FFFFu);
        if (rc && l < nlocal) {
            int pos = atomicAdd(&lh[l], 1);
            vals[pos] = rc - 1;
        }
    }
}

// MFMA GEMM: h[M,64](bf16) = (x @ W) * normc[row]
// 32 rows per wave (two 16-row tiles SHARING the B-fragments): halves
// per-row LDS B reads and halves block count (W re-stage 84 -> 42 MB).
// M = 163968 = 1281 * 128 exactly -> no tail handling.
__global__ __launch_bounds__(256) void k_gemm(const float* __restrict__ x, const float* __restrict__ W,
                                              const float* __restrict__ normc,
                                              __hip_bfloat16* __restrict__ h, int M) {
    __shared__ unsigned short sWT[COUT][CIN + 8];
    int t = threadIdx.x;
    for (int i = t; i < CIN * COUT; i += 256) {
        int k = i >> 6, c = i & 63;
        __hip_bfloat16 v = __float2bfloat16(W[i]);
        sWT[c][k] = *reinterpret_cast<unsigned short*>(&v);
    }
    __syncthreads();

    int wid  = t >> 6;
    int lane = t & 63;
    int r0 = blockIdx.x * 128 + wid * 32;
    if (r0 >= M) return;
    int row = lane & 15;
    int kg  = lane >> 4;

    s16x8 bf[4][4];
#pragma unroll
    for (int ct = 0; ct < 4; ++ct)
#pragma unroll
        for (int ks = 0; ks < 4; ++ks)
            bf[ct][ks] = *reinterpret_cast<const s16x8*>(&sWT[ct * 16 + row][ks * 32 + kg * 8]);

    s16x8 af[2][4];
#pragma unroll
    for (int half = 0; half < 2; ++half) {
        const float* xr = x + (size_t)(r0 + half * 16 + row) * CIN + kg * 8;
#pragma unroll
        for (int ks = 0; ks < 4; ++ks) {
            float4 a0 = *reinterpret_cast<const float4*>(xr + ks * 32);
            float4 a1 = *reinterpret_cast<const float4*>(xr + ks * 32 + 4);
            alignas(16) __hip_bfloat16 tmp[8];
            tmp[0] = __float2bfloat16(a0.x); tmp[1] = __float2bfloat16(a0.y);
            tmp[2] = __float2bfloat16(a0.z); tmp[3] = __float2bfloat16(a0.w);
            tmp[4] = __float2bfloat16(a1.x); tmp[5] = __float2bfloat16(a1.y);
            tmp[6] = __float2bfloat16(a1.z); tmp[7] = __float2bfloat16(a1.w);
            af[half][ks] = *reinterpret_cast<const s16x8*>(tmp);
        }
    }

    f32x4 acc[2][4];
#pragma unroll
    for (int half = 0; half < 2; ++half)
#pragma unroll
        for (int ct = 0; ct < 4; ++ct) acc[half][ct] = (f32x4)(0.f);
#pragma unroll
    for (int ks = 0; ks < 4; ++ks)
#pragma unroll
        for (int ct = 0; ct < 4; ++ct) {
            acc[0][ct] = __builtin_amdgcn_mfma_f32_16x16x32_bf16(af[0][ks], bf[ct][ks], acc[0][ct], 0, 0, 0);
            acc[1][ct] = __builtin_amdgcn_mfma_f32_16x16x32_bf16(af[1][ks], bf[ct][ks], acc[1][ct], 0, 0, 0);
        }

#pragma unroll
    for (int half = 0; half < 2; ++half) {
        int rb = r0 + half * 16;
        float sc[4];
#pragma unroll
        for (int j = 0; j < 4; ++j) sc[j] = normc[rb + kg * 4 + j];
#pragma unroll
        for (int ct = 0; ct < 4; ++ct) {
#pragma unroll
            for (int j = 0; j < 4; ++j) {
                int rr = rb + kg * 4 + j;
                h[(size_t)rr * COUT + ct * 16 + row] = __float2bfloat16(acc[half][ct][j] * sc[j]);
            }
        }
    }
}

// fused gather (unchanged round-18 uint4 form): wave = 32 nodes as
// 4 slots x 8 lane-groups; lane owns 16 B of the h row.
__global__ __launch_bounds__(256) void k_gather(const __hip_bfloat16* __restrict__ h, const int2* __restrict__ meta,
                                                const int* __restrict__ vals, const int* __restrict__ ord,
                                                const float* __restrict__ b, float* __restrict__ out, int N32) {
    int wid  = (blockIdx.x * 256 + threadIdx.x) >> 6;
    int lane = threadIdx.x & 63;
    if (wid >= N32) return;
    int g  = lane >> 3;
    int il = lane & 7;
    int base = wid * 32;
    f32x4 bb0 = *reinterpret_cast<const f32x4*>(&b[il * 8]);
    f32x4 bb1 = *reinterpret_cast<const f32x4*>(&b[il * 8 + 4]);

    int nid[4], bg[4], mm[4], mx[4];
    float nf[4];
    f32x4 acc0[4], acc1[4];
    int mmax = 0;
#pragma unroll
    for (int s = 0; s < 4; ++s) {
        nid[s] = ord[base + 8 * s + g];
        int2 Mi = meta[nid[s]];
        bg[s] = Mi.x;
        mm[s] = Mi.y & 0xFFFF;
        nf[s] = rsqrtf((float)(Mi.y >> 16));
        int m1 = max(mm[s], __shfl_xor(mm[s], 8));
        int m2 = max(m1, __shfl_xor(m1, 16));
        mx[s] = max(m2, __shfl_xor(m2, 32));
        acc0[s] = (f32x4)(0.f);
        acc1[s] = (f32x4)(0.f);
        mmax = max(mmax, mx[s]);
    }
    const char* hb = (const char*)h;
    for (int j = 0; j < mmax; ++j) {
#pragma unroll
        for (int s = 0; s < 4; ++s) {
            if (j < mx[s]) {
                bool act = j < mm[s];
                int e = act ? vals[bg[s] + j] : 0;
                uint4 hw = act ? *(const uint4*)(hb + (((size_t)(unsigned)e) << 7) + il * 16)
                               : make_uint4(0u, 0u, 0u, 0u);
                acc0[s].x += __uint_as_float(hw.x << 16);
                acc0[s].y += __uint_as_float(hw.x & 0xFFFF0000u);
                acc0[s].z += __uint_as_float(hw.y << 16);
                acc0[s].w += __uint_as_float(hw.y & 0xFFFF0000u);
                acc1[s].x += __uint_as_float(hw.z << 16);
                acc1[s].y += __uint_as_float(hw.z & 0xFFFF0000u);
                acc1[s].z += __uint_as_float(hw.w << 16);
                acc1[s].w += __uint_as_float(hw.w & 0xFFFF0000u);
            }
        }
    }
#pragma unroll
    for (int s = 0; s < 4; ++s) {
        f32x4 v0, v1;
        v0.x = fmaf(acc0[s].x, nf[s], bb0.x);
        v0.y = fmaf(acc0[s].y, nf[s], bb0.y);
        v0.z = fmaf(acc0[s].z, nf[s], bb0.z);
        v0.w = fmaf(acc0[s].w, nf[s], bb0.w);
        v1.x = fmaf(acc1[s].x, nf[s], bb1.x);
        v1.y = fmaf(acc1[s].y, nf[s], bb1.y);
        v1.z = fmaf(acc1[s].z, nf[s], bb1.z);
        v1.w = fmaf(acc1[s].w, nf[s], bb1.w);
        v0.x = v0.x > 0.f ? v0.x : (__expf(v0.x) - 1.0f);
        v0.y = v0.y > 0.f ? v0.y : (__expf(v0.y) - 1.0f);
        v0.z = v0.z > 0.f ? v0.z : (__expf(v0.z) - 1.0f);
        v0.w = v0.w > 0.f ? v0.w : (__expf(v0.w) - 1.0f);
        v1.x = v1.x > 0.f ? v1.x : (__expf(v1.x) - 1.0f);
        v1.y = v1.y > 0.f ? v1.y : (__expf(v1.y) - 1.0f);
        v1.z = v1.z > 0.f ? v1.z : (__expf(v1.z) - 1.0f);
        v1.w = v1.w > 0.f ? v1.w : (__expf(v1.w) - 1.0f);
        float* rowp = out + ((size_t)(unsigned)nid[s]) * COUT + il * 8;
        __builtin_nontemporal_store(v0, (f32x4*)rowp);
        __builtin_nontemporal_store(v1, (f32x4*)(rowp + 4));
    }
}

extern "C" void kernel_launch(void* const* d_in, const int* in_sizes, int n_in,
                              void* d_out, int out_size, void* d_ws, size_t ws_size,
                              hipStream_t stream) {
    const float* x    = (const float*)d_in[0];
    const float* W    = (const float*)d_in[1];
    const float* b    = (const float*)d_in[2];
    const int*   edge = (const int*)d_in[3];
    const int Mx = in_sizes[0] / CIN;     // coarse rows (163968)
    const int E  = in_sizes[3] / 2;       // directed edges (3932160)
    const int N  = out_size / COUT;       // fine nodes (655360)
    const int EPS = E / BSAMP;            // edges per sample (61440)

    const int* src = edge;
    const int* dst = edge + E;

    char* ws = (char*)d_ws;
    int2*  meta   = (int2*)ws;     ws += (size_t)N * 8;
    int*   cur    = (int*)ws;      ws += (256 * CPAD + 256) * 4;   // padded cursors + gctr
    float* normc  = (float*)ws;    ws += (size_t)Mx * 4;
    int*   ord    = (int*)ws;      ws += (size_t)N * 4;
    __hip_bfloat16* h = (__hip_bfloat16*)ws;
    unsigned* pk  = (unsigned*)ws; // aliases h: pk dead before k_gemm writes h
    {
        size_t hbytes  = (size_t)Mx * COUT * 2;                    // 20,987,904
        size_t pkbytes = (size_t)BSAMP * NRNG * SEGCAP * 4;        // 20,971,520
        ws += (hbytes > pkbytes ? hbytes : pkbytes);
    }
    int*   vals   = (int*)ws;      // up to E + Mx entries (4B each)

    int* gctr = cur + 256 * CPAD;
    const int bps = (EPS / 4 + 511) / 512;   // prep blocks per sample (=30)
    const int nzero = 256 * CPAD + 1;

    hipMemsetAsync(cur, 0, (size_t)nzero * 4, stream);
    k_prep  <<<BSAMP * bps, 256, 0, stream>>>((const int4*)src, (const int4*)dst, pk, cur, EPS, bps);
    k_build <<<BSAMP * NRNG, HT, 0, stream>>>(pk, cur, meta, normc, vals, ord, gctr);
    k_gemm  <<<(Mx + 127) / 128, 256, 0, stream>>>(x, W, normc, h, Mx);
    k_gather<<<((N / 32) * 64 + 255) / 256, 256, 0, stream>>>(h, meta, vals, ord, b, (float*)d_out, N / 32);
}

// Round 21
// 125.468 us; speedup vs baseline: 1.0144x; 1.0144x over previous
//
#include <hip/hip_runtime.h>
#include <hip/hip_bf16.h>
#include <math.h>

#define CIN 128
#define COUT 64
#define BSAMP 64      // samples in batch (fixed by problem)
#define NFINE 10242   // fine nodes per sample (fixed by problem)
#define NCOARSE 2562  // coarse nodes per sample (fixed by problem)
#define NRNG 4        // node-ranges per sample
#define RS 2561       // ceil(NFINE / NRNG)
#define HT 1024       // threads for build kernel
#define NCLS 17       // degree classes 0..15 and >=16
#define SEGCAP 20480  // slots per (sample,range) segment; mean 15360, sigma ~107
#define CPAD 16       // cursor padding (ints) -> one 64 B line per cursor
#define EPB 2048      // edges per prep block (8 per thread)

typedef float f32x4 __attribute__((ext_vector_type(4)));
typedef short s16x8 __attribute__((ext_vector_type(8)));

// cursors (padded) + gctr
__global__ __launch_bounds__(256) void k_zero(int* __restrict__ cur, int n) {
    int i = blockIdx.x * 256 + threadIdx.x;
    if (i < n) cur[i] = 0;
}

// Bucket-scatter prep with per-block LDS staging; 8 edges per thread
// (two int4 pairs) halves per-block fixed costs vs the 4-edge version.
__global__ __launch_bounds__(256) void k_prep(const int4* __restrict__ src4, const int4* __restrict__ dst4,
                                              unsigned* __restrict__ pk, int* __restrict__ cur,
                                              int EPS, int bps) {
    __shared__ unsigned bbuf[NRNG][EPB];
    __shared__ int bcnt[NRNG];
    __shared__ int gb[NRNG];
    int t = threadIdx.x;
    int b  = blockIdx.x / bps;
    int il0 = (blockIdx.x % bps) * 512 + t;
    int n4 = EPS / 4;
    if (t < NRNG) bcnt[t] = 0;
    __syncthreads();
    int base = b * NFINE;
#pragma unroll
    for (int half = 0; half < 2; ++half) {
        int il = il0 + half * 256;
        if (il < n4) {
            size_t i = (size_t)b * n4 + il;
            int4 s = src4[i], d = dst4[i];
#define COMP(c) { \
            int ls = d.c - base; \
            if ((unsigned)ls < (unsigned)NFINE) { \
                int rri = ls / RS; \
                int sl = s.c - base; \
                unsigned rc = ((unsigned)sl < (unsigned)NCOARSE) ? (unsigned)(b * NCOARSE + sl + 1) : 0u; \
                unsigned pv = ((unsigned)(ls - rri * RS) << 18) | rc; \
                int p = atomicAdd(&bcnt[rri], 1); \
                bbuf[rri][p] = pv; } }
            COMP(x) COMP(y) COMP(z) COMP(w)
#undef COMP
        }
    }
    __syncthreads();
    if (t < NRNG) gb[t] = atomicAdd(&cur[(b * NRNG + t) * CPAD], bcnt[t]);
    __syncthreads();
#pragma unroll
    for (int rr = 0; rr < NRNG; ++rr) {
        int n = bcnt[rr];
        int g0 = gb[rr];
        unsigned* seg = pk + (size_t)(b * NRNG + rr) * SEGCAP;
        for (int i = t; i < n; i += 256) {
            int pos = g0 + i;
            if (pos < SEGCAP) seg[pos] = bbuf[rr][i];
        }
    }
}

// CSR build. Scan over the 1024 threads is shfl wave-scan (6 steps) +
// 16-entry cross-wave scan: 2 barriers instead of 20.
__global__ __launch_bounds__(HT) void k_build(const unsigned* __restrict__ pk, const int* __restrict__ cur,
                                              int2* __restrict__ meta, float* __restrict__ normc,
                                              int* __restrict__ vals, int* __restrict__ ord,
                                              int* __restrict__ gctr) {
    __shared__ int   lh[RS];
    __shared__ int   wsum[16];
    __shared__ int   ccnt[NCLS];
    __shared__ int   gbase;
    int t = threadIdx.x;
    int lane = t & 63, wv = t >> 6;
    int b = blockIdx.x / NRNG, r = blockIdx.x % NRNG;
    int lo = r * RS;
    int nlocal = min(RS, NFINE - lo);
    int rebase = b * NFINE + lo;
    for (int j = t; j < nlocal; j += HT) lh[j] = 0;
    if (t < NCLS) ccnt[t] = 0;
    __syncthreads();

    const unsigned* seg = pk + (size_t)(b * NRNG + r) * SEGCAP;
    int ne = min(cur[(b * NRNG + r) * CPAD], SEGCAP);
    for (int i = t; i < ne; i += HT) {
        unsigned u = seg[i];
        int l = (int)(u >> 18);
        int rc = (int)(u & 0x3FFFFu);
        if (l < nlocal) atomicAdd(&lh[l], 1 + (rc ? 65536 : 0));
    }
    __syncthreads();

    int mj[3], degk[3], selfk[3], cls[3], rank[3];
    int psum = 0;
#pragma unroll
    for (int k = 0; k < 3; ++k) {
        int idx = t + k * HT;
        int m = 0, dg = 0, sf = 0;
        if (idx < nlocal) {
            int c = lh[idx];
            int slocal = lo + idx;
            sf = (slocal < NCOARSE) ? (b * NCOARSE + slocal + 1) : 0;
            m = (c >> 16) + (sf ? 1 : 0);
            dg = (c & 0xFFFF) + 1;
            cls[k] = min(m, NCLS - 1);
            rank[k] = atomicAdd(&ccnt[cls[k]], 1);
        }
        mj[k] = m; degk[k] = dg; selfk[k] = sf;
        psum += m;
    }
    // inclusive scan of psum over 1024 threads: wave shfl-scan + cross-wave
    int v = psum;
#pragma unroll
    for (int off = 1; off < 64; off <<= 1) {
        int u = __shfl_up(v, off);
        if (lane >= off) v += u;
    }
    if (lane == 63) wsum[wv] = v;
    __syncthreads();
    if (t == 0) {
        int run = 0;
#pragma unroll
        for (int w = 0; w < 16; ++w) { int x2 = wsum[w]; wsum[w] = run; run += x2; }
        int run2 = 0;
#pragma unroll
        for (int c = 0; c < NCLS; ++c) { int x2 = ccnt[c]; ccnt[c] = run2; run2 += x2; }
    }
    __syncthreads();
    int inc = v + wsum[wv];                        // inclusive prefix for this thread
    if (t == HT - 1) gbase = atomicAdd(gctr, inc); // inc == block total at last thread
    __syncthreads();

    int run = gbase + inc - psum;                  // exclusive base for this thread
#pragma unroll
    for (int k = 0; k < 3; ++k) {
        int idx = t + k * HT;
        if (idx < nlocal) {
            int gf = rebase + idx;
            meta[gf] = make_int2(run, mj[k] | (degk[k] << 16));
            ord[rebase + ccnt[cls[k]] + rank[k]] = gf;
            int cur2 = run;
            if (selfk[k]) {
                int rv = selfk[k] - 1;
                normc[rv] = rsqrtf((float)degk[k]);
                vals[cur2] = rv;
                ++cur2;
            }
            lh[idx] = cur2;
            run += mj[k];
        }
    }
    __syncthreads();

    for (int i = t; i < ne; i += HT) {
        unsigned u = seg[i];
        int l = (int)(u >> 18);
        int rc = (int)(u & 0x3FFFFu);
        if (rc && l < nlocal) {
            int pos = atomicAdd(&lh[l], 1);
            vals[pos] = rc - 1;
        }
    }
}

// MFMA GEMM (round-16/19 version, empirically best): one 16-row tile per wave,
// h[M,64](bf16) = (x @ W) * normc[row]
__global__ __launch_bounds__(256) void k_gemm(const float* __restrict__ x, const float* __restrict__ W,
                                              const float* __restrict__ normc,
                                              __hip_bfloat16* __restrict__ h, int M) {
    __shared__ unsigned short sWT[COUT][CIN + 8];
    int t = threadIdx.x;
    for (int i = t; i < CIN * COUT; i += 256) {
        int k = i >> 6, c = i & 63;
        __hip_bfloat16 v = __float2bfloat16(W[i]);
        sWT[c][k] = *reinterpret_cast<unsigned short*>(&v);
    }
    __syncthreads();

    int wid  = t >> 6;
    int lane = t & 63;
    int r0 = blockIdx.x * 64 + wid * 16;
    if (r0 >= M) return;
    int row = lane & 15;
    int kg  = lane >> 4;

    s16x8 bf[4][4];
#pragma unroll
    for (int ct = 0; ct < 4; ++ct)
#pragma unroll
        for (int ks = 0; ks < 4; ++ks)
            bf[ct][ks] = *reinterpret_cast<const s16x8*>(&sWT[ct * 16 + row][ks * 32 + kg * 8]);

    const float* xr = x + (size_t)(r0 + row) * CIN + kg * 8;
    s16x8 af[4];
#pragma unroll
    for (int ks = 0; ks < 4; ++ks) {
        float4 a0 = *reinterpret_cast<const float4*>(xr + ks * 32);
        float4 a1 = *reinterpret_cast<const float4*>(xr + ks * 32 + 4);
        alignas(16) __hip_bfloat16 tmp[8];
        tmp[0] = __float2bfloat16(a0.x); tmp[1] = __float2bfloat16(a0.y);
        tmp[2] = __float2bfloat16(a0.z); tmp[3] = __float2bfloat16(a0.w);
        tmp[4] = __float2bfloat16(a1.x); tmp[5] = __float2bfloat16(a1.y);
        tmp[6] = __float2bfloat16(a1.z); tmp[7] = __float2bfloat16(a1.w);
        af[ks] = *reinterpret_cast<const s16x8*>(tmp);
    }

    f32x4 acc[4] = { (f32x4)(0.f), (f32x4)(0.f), (f32x4)(0.f), (f32x4)(0.f) };
#pragma unroll
    for (int ks = 0; ks < 4; ++ks)
#pragma unroll
        for (int ct = 0; ct < 4; ++ct)
            acc[ct] = __builtin_amdgcn_mfma_f32_16x16x32_bf16(af[ks], bf[ct][ks], acc[ct], 0, 0, 0);

    float sc[4];
#pragma unroll
    for (int j = 0; j < 4; ++j) sc[j] = normc[r0 + kg * 4 + j];
#pragma unroll
    for (int ct = 0; ct < 4; ++ct) {
#pragma unroll
        for (int j = 0; j < 4; ++j) {
            int rr = r0 + kg * 4 + j;
            h[(size_t)rr * COUT + ct * 16 + row] = __float2bfloat16(acc[ct][j] * sc[j]);
        }
    }
}

// fused gather (round-18 uint4 form): wave = 32 nodes as 4 slots x 8
// lane-groups; lane owns 16 B of the h row.
__global__ __launch_bounds__(256) void k_gather(const __hip_bfloat16* __restrict__ h, const int2* __restrict__ meta,
                                                const int* __restrict__ vals, const int* __restrict__ ord,
                                                const float* __restrict__ b, float* __restrict__ out, int N32) {
    int wid  = (blockIdx.x * 256 + threadIdx.x) >> 6;
    int lane = threadIdx.x & 63;
    if (wid >= N32) return;
    int g  = lane >> 3;
    int il = lane & 7;
    int base = wid * 32;
    f32x4 bb0 = *reinterpret_cast<const f32x4*>(&b[il * 8]);
    f32x4 bb1 = *reinterpret_cast<const f32x4*>(&b[il * 8 + 4]);

    int nid[4], bg[4], mm[4], mx[4];
    float nf[4];
    f32x4 acc0[4], acc1[4];
    int mmax = 0;
#pragma unroll
    for (int s = 0; s < 4; ++s) {
        nid[s] = ord[base + 8 * s + g];
        int2 Mi = meta[nid[s]];
        bg[s] = Mi.x;
        mm[s] = Mi.y & 0xFFFF;
        nf[s] = rsqrtf((float)(Mi.y >> 16));
        int m1 = max(mm[s], __shfl_xor(mm[s], 8));
        int m2 = max(m1, __shfl_xor(m1, 16));
        mx[s] = max(m2, __shfl_xor(m2, 32));
        acc0[s] = (f32x4)(0.f);
        acc1[s] = (f32x4)(0.f);
        mmax = max(mmax, mx[s]);
    }
    const char* hb = (const char*)h;
    for (int j = 0; j < mmax; ++j) {
#pragma unroll
        for (int s = 0; s < 4; ++s) {
            if (j < mx[s]) {
                bool act = j < mm[s];
                int e = act ? vals[bg[s] + j] : 0;
                uint4 hw = act ? *(const uint4*)(hb + (((size_t)(unsigned)e) << 7) + il * 16)
                               : make_uint4(0u, 0u, 0u, 0u);
                acc0[s].x += __uint_as_float(hw.x << 16);
                acc0[s].y += __uint_as_float(hw.x & 0xFFFF0000u);
                acc0[s].z += __uint_as_float(hw.y << 16);
                acc0[s].w += __uint_as_float(hw.y & 0xFFFF0000u);
                acc1[s].x += __uint_as_float(hw.z << 16);
                acc1[s].y += __uint_as_float(hw.z & 0xFFFF0000u);
                acc1[s].z += __uint_as_float(hw.w << 16);
                acc1[s].w += __uint_as_float(hw.w & 0xFFFF0000u);
            }
        }
    }
#pragma unroll
    for (int s = 0; s < 4; ++s) {
        f32x4 v0, v1;
        v0.x = fmaf(acc0[s].x, nf[s], bb0.x);
        v0.y = fmaf(acc0[s].y, nf[s], bb0.y);
        v0.z = fmaf(acc0[s].z, nf[s], bb0.z);
        v0.w = fmaf(acc0[s].w, nf[s], bb0.w);
        v1.x = fmaf(acc1[s].x, nf[s], bb1.x);
        v1.y = fmaf(acc1[s].y, nf[s], bb1.y);
        v1.z = fmaf(acc1[s].z, nf[s], bb1.z);
        v1.w = fmaf(acc1[s].w, nf[s], bb1.w);
        v0.x = v0.x > 0.f ? v0.x : (__expf(v0.x) - 1.0f);
        v0.y = v0.y > 0.f ? v0.y : (__expf(v0.y) - 1.0f);
        v0.z = v0.z > 0.f ? v0.z : (__expf(v0.z) - 1.0f);
        v0.w = v0.w > 0.f ? v0.w : (__expf(v0.w) - 1.0f);
        v1.x = v1.x > 0.f ? v1.x : (__expf(v1.x) - 1.0f);
        v1.y = v1.y > 0.f ? v1.y : (__expf(v1.y) - 1.0f);
        v1.z = v1.z > 0.f ? v1.z : (__expf(v1.z) - 1.0f);
        v1.w = v1.w > 0.f ? v1.w : (__expf(v1.w) - 1.0f);
        float* rowp = out + ((size_t)(unsigned)nid[s]) * COUT + il * 8;
        __builtin_nontemporal_store(v0, (f32x4*)rowp);
        __builtin_nontemporal_store(v1, (f32x4*)(rowp + 4));
    }
}

extern "C" void kernel_launch(void* const* d_in, const int* in_sizes, int n_in,
                              void* d_out, int out_size, void* d_ws, size_t ws_size,
                              hipStream_t stream) {
    const float* x    = (const float*)d_in[0];
    const float* W    = (const float*)d_in[1];
    const float* b    = (const float*)d_in[2];
    const int*   edge = (const int*)d_in[3];
    const int Mx = in_sizes[0] / CIN;     // coarse rows (163968)
    const int E  = in_sizes[3] / 2;       // directed edges (3932160)
    const int N  = out_size / COUT;       // fine nodes (655360)
    const int EPS = E / BSAMP;            // edges per sample (61440)

    const int* src = edge;
    const int* dst = edge + E;

    char* ws = (char*)d_ws;
    int2*  meta   = (int2*)ws;     ws += (size_t)N * 8;
    int*   cur    = (int*)ws;      ws += (256 * CPAD + 256) * 4;   // padded cursors + gctr
    float* normc  = (float*)ws;    ws += (size_t)Mx * 4;
    int*   ord    = (int*)ws;      ws += (size_t)N * 4;
    __hip_bfloat16* h = (__hip_bfloat16*)ws;
    unsigned* pk  = (unsigned*)ws; // aliases h: pk dead before k_gemm writes h
    {
        size_t hbytes  = (size_t)Mx * COUT * 2;                    // 20,987,904
        size_t pkbytes = (size_t)BSAMP * NRNG * SEGCAP * 4;        // 20,971,520
        ws += (hbytes > pkbytes ? hbytes : pkbytes);
    }
    int*   vals   = (int*)ws;      // up to E + Mx entries (4B each)

    int* gctr = cur + 256 * CPAD;
    const int bps = (EPS / 4 + 511) / 512;   // prep blocks per sample (=30)
    const int nzero = 256 * CPAD + 1;

    k_zero  <<<(nzero + 255) / 256, 256, 0, stream>>>(cur, nzero);
    k_prep  <<<BSAMP * bps, 256, 0, stream>>>((const int4*)src, (const int4*)dst, pk, cur, EPS, bps);
    k_build <<<BSAMP * NRNG, HT, 0, stream>>>(pk, cur, meta, normc, vals, ord, gctr);
    k_gemm  <<<(Mx + 63) / 64, 256, 0, stream>>>(x, W, normc, h, Mx);
    k_gather<<<((N / 32) * 64 + 255) / 256, 256, 0, stream>>>(h, meta, vals, ord, b, (float*)d_out, N / 32);
}